// Round 8
// baseline (248.870 us; speedup 1.0000x reference)
//
#include <hip/hip_runtime.h>
#include <math.h>

// B=32, F=1000, D=1024; OUT = 1+22+1+22+1+128 = 175
#define D_DIM  1024
#define OUT_N  175
#define HID_N  128
#define BM     64
#define NT     32               // 32-k steps over K=1024
#define NFRAG  11               // N tiles of 16 (176 padded)
#define FRAG_STRIDE 512         // shorts per (j,t) B-fragment: 64 lanes * 8

#define V_OFF   1
#define VG_OFF  23
#define N_OFF   24
#define NG_OFF  46
#define HF_OFF  47

#define LOG_F0_MIN 4.3820266346738812f   // ln(80)
#define LOG_F0_MAX 6.9077552789821368f   // ln(1000)
#define PI_F       3.14159265358979323846f

typedef __attribute__((ext_vector_type(8))) short s16x8;   // 8 bf16 = 4 VGPR MFMA frag
typedef __attribute__((ext_vector_type(4))) short s16x4;
typedef __attribute__((ext_vector_type(4))) float f32x4;

// fp32 -> bf16 bits, round-to-nearest-even (pure integer)
static __device__ __forceinline__ short f2bf(float f) {
    unsigned u = __float_as_uint(f);
    unsigned r = (u + 0x7fffu + ((u >> 16) & 1u)) >> 16;
    return (short)r;
}
static __device__ __forceinline__ float bf2f(short s) {
    return __uint_as_float(((unsigned)(unsigned short)s) << 16);
}

// ---------- pre-kernel: W (fp32) -> bf16 hi/lo in MFMA-FRAGMENT order ----------
// frag (j,t) at ((j*NT)+t)*FRAG_STRIDE; within: lane*8+e
//   = W[n=16j+(lane&15)][k=32t+(lane>>4)*8+e]  (zeros for n>=175)
__global__ __launch_bounds__(64) void build_wfrag(
    const float* __restrict__ W, short* __restrict__ whiF, short* __restrict__ wloF)
{
    const int ft   = blockIdx.x;           // j*32+t
    const int j    = ft >> 5;
    const int t    = ft & 31;
    const int lane = threadIdx.x;
    const int n    = 16 * j + (lane & 15);
    const int k    = 32 * t + (lane >> 4) * 8;

    float v[8];
    if (n < OUT_N) {
        float4 p0 = *(const float4*)(W + (size_t)n * D_DIM + k);
        float4 p1 = *(const float4*)(W + (size_t)n * D_DIM + k + 4);
        v[0] = p0.x; v[1] = p0.y; v[2] = p0.z; v[3] = p0.w;
        v[4] = p1.x; v[5] = p1.y; v[6] = p1.z; v[7] = p1.w;
    } else {
        #pragma unroll
        for (int e = 0; e < 8; ++e) v[e] = 0.f;
    }
    s16x8 hv, lv;
    #pragma unroll
    for (int e = 0; e < 8; ++e) {
        short hb = f2bf(v[e]);
        hv[e] = hb;
        lv[e] = f2bf(v[e] - bf2f(hb));
    }
    const size_t off = ((size_t)ft * 64 + lane) * 8;
    *(s16x8*)(whiF + off) = hv;
    *(s16x8*)(wloF + off) = lv;
}

// ---------- main fused kernel: barrier-free K-loop, A in registers ----------
// LDS: epilogue yS[64][49] only (12544 B)
__global__ __launch_bounds__(256) void glottal_main(
    const float* __restrict__ h, const short* __restrict__ whiF,
    const short* __restrict__ wloF, const float* __restrict__ bias,
    float* __restrict__ out, int R)
{
    __shared__ float yS[64][49];

    const int tid  = threadIdx.x;
    const int r0   = blockIdx.x * BM;

    const int lane = tid & 63;
    const int wid  = tid >> 6;       // 0..3 = jg
    const int c    = lane & 15;
    const int kg   = lane >> 4;
    const int jg   = wid;
    const int jcnt = (jg < 3) ? 3 : 2;

    // A row pointers: lane reads rows r0+16*mm+c, k-offset kg*8 (+32 per t)
    const float* aRow[4];
    #pragma unroll
    for (int mm = 0; mm < 4; ++mm) {
        int gr = r0 + 16 * mm + c; if (gr >= R) gr = R - 1;
        aRow[mm] = h + (size_t)gr * D_DIM + kg * 8;
    }

    // B fragment pointers (fragment-ordered workspace, L2-resident)
    const short* bhP[3];
    const short* blP[3];
    #pragma unroll
    for (int jj = 0; jj < 3; ++jj) {
        int j = 3 * jg + jj; if (j > NFRAG - 1) j = NFRAG - 1;
        bhP[jj] = whiF + (size_t)j * NT * FRAG_STRIDE + lane * 8;
        blP[jj] = wloF + (size_t)j * NT * FRAG_STRIDE + lane * 8;
    }

    f32x4 acc[4][3];
    #pragma unroll
    for (int mm = 0; mm < 4; ++mm)
        #pragma unroll
        for (int jj = 0; jj < 3; ++jj) acc[mm][jj] = f32x4{0.f, 0.f, 0.f, 0.f};

    // ---- prologue: load t=0 ----
    float4 aC[4][2];
    s16x8  bhC[3], blC[3];
    #pragma unroll
    for (int mm = 0; mm < 4; ++mm) {
        aC[mm][0] = *(const float4*)(aRow[mm]);
        aC[mm][1] = *(const float4*)(aRow[mm] + 4);
    }
    #pragma unroll
    for (int jj = 0; jj < 3; ++jj) if (jj < jcnt) {
        bhC[jj] = *(const s16x8*)(bhP[jj]);
        blC[jj] = *(const s16x8*)(blP[jj]);
    }

    #pragma unroll 2
    for (int t = 0; t < NT; ++t) {
        // ---- depth-1 register prefetch of t+1 (no barrier ever drains it) ----
        float4 aN[4][2];
        s16x8  bhN[3], blN[3];
        const bool more = (t + 1 < NT);
        if (more) {
            #pragma unroll
            for (int mm = 0; mm < 4; ++mm) {
                aN[mm][0] = *(const float4*)(aRow[mm] + (t + 1) * 32);
                aN[mm][1] = *(const float4*)(aRow[mm] + (t + 1) * 32 + 4);
            }
            #pragma unroll
            for (int jj = 0; jj < 3; ++jj) if (jj < jcnt) {
                bhN[jj] = *(const s16x8*)(bhP[jj] + (size_t)(t + 1) * FRAG_STRIDE);
                blN[jj] = *(const s16x8*)(blP[jj] + (size_t)(t + 1) * FRAG_STRIDE);
            }
        }

        // ---- per m-frag: in-register split to bf16 hi/lo, then MFMA ----
        #pragma unroll
        for (int mm = 0; mm < 4; ++mm) {
            s16x8 ah, al;
            {
                float v;
                short hb;
                v = aC[mm][0].x; hb = f2bf(v); ah[0] = hb; al[0] = f2bf(v - bf2f(hb));
                v = aC[mm][0].y; hb = f2bf(v); ah[1] = hb; al[1] = f2bf(v - bf2f(hb));
                v = aC[mm][0].z; hb = f2bf(v); ah[2] = hb; al[2] = f2bf(v - bf2f(hb));
                v = aC[mm][0].w; hb = f2bf(v); ah[3] = hb; al[3] = f2bf(v - bf2f(hb));
                v = aC[mm][1].x; hb = f2bf(v); ah[4] = hb; al[4] = f2bf(v - bf2f(hb));
                v = aC[mm][1].y; hb = f2bf(v); ah[5] = hb; al[5] = f2bf(v - bf2f(hb));
                v = aC[mm][1].z; hb = f2bf(v); ah[6] = hb; al[6] = f2bf(v - bf2f(hb));
                v = aC[mm][1].w; hb = f2bf(v); ah[7] = hb; al[7] = f2bf(v - bf2f(hb));
            }
            #pragma unroll
            for (int jj = 0; jj < 3; ++jj) if (jj < jcnt) {
                acc[mm][jj] = __builtin_amdgcn_mfma_f32_16x16x32_bf16(ah, bhC[jj], acc[mm][jj], 0, 0, 0);
                acc[mm][jj] = __builtin_amdgcn_mfma_f32_16x16x32_bf16(ah, blC[jj], acc[mm][jj], 0, 0, 0);
                acc[mm][jj] = __builtin_amdgcn_mfma_f32_16x16x32_bf16(al, bhC[jj], acc[mm][jj], 0, 0, 0);
            }
        }

        // ---- rotate prefetch -> current ----
        if (more) {
            #pragma unroll
            for (int mm = 0; mm < 4; ++mm) {
                aC[mm][0] = aN[mm][0];
                aC[mm][1] = aN[mm][1];
            }
            #pragma unroll
            for (int jj = 0; jj < 3; ++jj) if (jj < jcnt) {
                bhC[jj] = bhN[jj];
                blC[jj] = blN[jj];
            }
        }
    }

    const size_t Rz = (size_t)R;

    // ---- epilogue: h_feat direct from regs; cols 0..46 via small yS ----
    // D frag: col = 16j + c, row = 16*mm + 4*kg + r
    #pragma unroll
    for (int jj = 0; jj < 3; ++jj) if (jj < jcnt) {
        const int j   = 3 * jg + jj;
        const int col = 16 * j + c;
        const float bb = (col < OUT_N) ? bias[col] : 0.f;
        #pragma unroll
        for (int mm = 0; mm < 4; ++mm) {
            const int rb = 16 * mm + (kg << 2);
            if (col >= HF_OFF && col < OUT_N) {
                #pragma unroll
                for (int r = 0; r < 4; ++r) {
                    int gr = r0 + rb + r;
                    if (gr < R)
                        out[Rz + (size_t)gr * HID_N + (col - HF_OFF)] = acc[mm][jj][r] + bb;
                }
            } else if (col < HF_OFF) {
                #pragma unroll
                for (int r = 0; r < 4; ++r)
                    yS[rb + r][col] = acc[mm][jj][r] + bb;
            }
        }
    }
    __syncthreads();   // single barrier in the whole kernel

    // ---- scalars + LPC: 2 threads/row (half 0 = voice+f0, half 1 = noise) ----
    if (tid < 2 * BM) {
        const int rr   = tid >> 1;
        const int half = tid & 1;
        const int gr   = r0 + rr;
        if (gr < R) {
            const float* yrow = yS[rr];

            if (half == 0) {
                float s = 1.f / (1.f + expf(-yrow[0]));
                out[gr] = expf(s * (LOG_F0_MAX - LOG_F0_MIN) + LOG_F0_MIN);
            }

            const int lbase = half ? N_OFF  : V_OFF;
            const int gidx  = half ? NG_OFF : VG_OFF;
            float*    gout  = out + (half ? Rz * 152 : Rz * 129);
            float*    lout  = out + (half ? Rz * 153 : Rz * 130);

            gout[gr] = expf(yrow[gidx]);

            float poly[23];
            poly[0] = 1.f;
            #pragma unroll
            for (int j = 1; j < 23; ++j) poly[j] = 0.f;

            #pragma unroll
            for (int i = 0; i < 11; ++i) {
                float l0  = yrow[lbase + 2 * i];
                float l1  = yrow[lbase + 2 * i + 1];
                float mag = 0.99f / (1.f + expf(-l0));
                float ph  = PI_F   / (1.f + expf(-l1));
                float a1  = -2.f * mag * cosf(ph);
                float a2  = mag * mag;
                #pragma unroll
                for (int j = 22; j >= 2; --j)
                    poly[j] = fmaf(a1, poly[j - 1], fmaf(a2, poly[j - 2], poly[j]));
                poly[1] = fmaf(a1, poly[0], poly[1]);
            }

            #pragma unroll
            for (int j = 0; j < 22; ++j)
                lout[(size_t)gr * 22 + j] = poly[j + 1];
        }
    }
}

extern "C" void kernel_launch(void* const* d_in, const int* in_sizes, int n_in,
                              void* d_out, int out_size, void* d_ws, size_t ws_size,
                              hipStream_t stream) {
    const float* h    = (const float*)d_in[0];
    const float* W    = (const float*)d_in[1];
    const float* bias = (const float*)d_in[2];
    float* out        = (float*)d_out;

    const int R = in_sizes[0] / D_DIM;          // 32000
    const int blocks = (R + BM - 1) / BM;       // 500

    short* whiF = (short*)d_ws;                            // 352*512 shorts
    short* wloF = whiF + (size_t)NFRAG * NT * FRAG_STRIDE; // total 720896 B

    build_wfrag<<<NFRAG * NT, 64, 0, stream>>>(W, whiF, wloF);
    glottal_main<<<blocks, 256, 0, stream>>>(h, whiF, wloF, bias, out, R);
}